// Round 4
// baseline (304.000 us; speedup 1.0000x reference)
//
#include <hip/hip_runtime.h>

// ---------------------------------------------------------------------------
// MultiQueryAttention: B=4 S=2048 E=1024 H=16 D=64 Q=4
// ref: q=x@Wq^T+bq (per qi), k=x@Wk^T+bk, v=x@Wv^T+bv
//      scores[qi,b,s,h,g] = dot_d(q[h],k[g])/8 ; softmax over g (16 heads!)
//      out[qi,b,s,h,d] = sum_g p*v[g,d]
//      t[b, 128h + s/16, 64(s%16)+d] = sum_qi out   (torch transpose+reshape)
//      final = t @ Wo^T + bo   (fp32 out)
// ---------------------------------------------------------------------------

typedef __bf16 bf16x8 __attribute__((ext_vector_type(8)));
typedef float f32x4 __attribute__((ext_vector_type(4)));
typedef float f32x16 __attribute__((ext_vector_type(16)));

__device__ __forceinline__ unsigned short f2b(float f) {
  unsigned u = __float_as_uint(f);
  return (unsigned short)((u + 0x7fffu + ((u >> 16) & 1u)) >> 16);  // RNE
}

__device__ __forceinline__ void async16(const void* g, void* l) {
  __builtin_amdgcn_global_load_lds(
      (const __attribute__((address_space(1))) void*)g,
      (__attribute__((address_space(3))) void*)l, 16, 0, 0);
}

// ------------------- fused fp32->bf16 convert + bias concat ------------------
__global__ __launch_bounds__(256) void cvt_all(
    const float* __restrict__ x, const float* __restrict__ Wq, const float* __restrict__ Wk,
    const float* __restrict__ Wv, const float* __restrict__ Wo, const float* __restrict__ bq,
    const float* __restrict__ bk, const float* __restrict__ bv,
    unsigned short* __restrict__ xb, unsigned short* __restrict__ wcat,
    unsigned short* __restrict__ wo_b, float* __restrict__ biascat) {
  if (blockIdx.x >= 15360) {
    int j = (blockIdx.x - 15360) * 256 + threadIdx.x;  // 0..6143
    if (j < 6144) {
      float v = (j < 4096) ? bq[j] : (j < 5120 ? bk[j - 4096] : bv[j - 5120]);
      biascat[j] = v;
    }
    return;
  }
  int i = blockIdx.x * 256 + threadIdx.x;
  const float* s;
  unsigned short* d;
  int off;
  if (i < 2097152)      { s = x;  d = xb;             off = i; }
  else if (i < 3145728) { s = Wq; d = wcat;           off = i - 2097152; }
  else if (i < 3407872) { s = Wk; d = wcat + 4194304; off = i - 3145728; }
  else if (i < 3670016) { s = Wv; d = wcat + 5242880; off = i - 3407872; }
  else                  { s = Wo; d = wo_b;           off = i - 3670016; }
  float4 v = ((const float4*)s)[off];
  uint2 o;
  o.x = (unsigned)f2b(v.x) | ((unsigned)f2b(v.y) << 16);
  o.y = (unsigned)f2b(v.z) | ((unsigned)f2b(v.w) << 16);
  ((uint2*)d)[off] = o;
}

// ------------------ 256x256 deep-pipelined GEMM (QKV) -----------------------
// C = A * Bt^T + bias, bf16 out. M%256==0, N%256==0, K%32==0, K>=96.
// 8 waves as 2(M)x4(N); per-wave C = 128x64 = 4x2 of 32x32 MFMA frags.
// LDS: 4-deep ring of BK=32 K-tiles (A:16KB + B:16KB each) = 128 KiB.
//
// PAIR-ROW SWIZZLE (R2, verified conflict-free: SQ_LDS_BANK_CONFLICT==0):
// granule g (16B) of row r lives at phys slot p = (2g+(r&1)) ^ ((r>>1)&7)
// within pair (r>>1). Store: linear LDS dest (global_load_lds), pre-swizzled
// GLOBAL source. Read: p = (4ks + 2*lhi + (l31&1)) ^ ((l31>>1)&7).
//
// R3: ONE barrier per K-tile (4-deep ring makes intra-iter barriers
// redundant). R4: prefetch DISTANCE 2 — stage tile kt+3 at the TOP of iter
// kt, so tile kt+1's loads have ~2 iterations (~5700cy) in flight when the
// end-of-iter vmcnt(8) retires them (R3's distance-1 vmcnt(4) waited on
// loads only ~1 iter old -> partial drain every iter, MfmaUtil capped 39%).
// WAR safe: buffer (kt+3)&3 = (kt-1)&3 was last read before the previous
// barrier. B-fragments are ds_read FIRST so the first MFMA's operands
// complete after ~6 returns (counted lgkmcnt) instead of 9.
__global__ __launch_bounds__(512, 2) void gemm256(
    const unsigned short* __restrict__ A, const unsigned short* __restrict__ Bt,
    const float* __restrict__ bias, unsigned short* __restrict__ C,
    int M, int N, int K) {
  __shared__ __align__(16) unsigned short As[4][8192];
  __shared__ __align__(16) unsigned short Bs[4][8192];
  const int t = threadIdx.x;
  const int lane = t & 63, w = t >> 6;
  const int l31 = lane & 31, lhi = lane >> 5;
  const int wm = (w >> 2) * 128, wn = (w & 3) * 64;
  const int bm0 = blockIdx.y * 256, bn0 = blockIdx.x * 256;

  // ---- staging: thread t handles slot t (rows 0..127) and t+512 (rows
  // 128..255); source pre-swizzled, LDS dest linear.
  const int p0 = t & 7, pr0 = t >> 3;
  const int u0 = p0 ^ (pr0 & 7);
  const size_t aoff0 = (size_t)(2 * pr0 + (u0 & 1)) * K + (u0 >> 1) * 8;
  const unsigned short* aS0 = A + (size_t)bm0 * K + aoff0;
  const unsigned short* aS1 = aS0 + (size_t)128 * K;  // slot t+512: same u (64%8==0)
  const unsigned short* bS0 = Bt + (size_t)bn0 * K + aoff0;
  const unsigned short* bS1 = bS0 + (size_t)128 * K;
  const int d0 = t * 8, d1 = d0 + 4096;  // linear LDS dests (elements)

  // ---- read offsets
  const int plo = 2 * lhi + (l31 & 1);
  const int pswz = (l31 >> 1) & 7;
  const int pg0 = ((0 + plo) ^ pswz) * 8;  // ks=0
  const int pg1 = ((4 + plo) ^ pswz) * 8;  // ks=1
  int prA[4], prB[2];
#pragma unroll
  for (int mi = 0; mi < 4; ++mi) prA[mi] = ((wm + mi * 32 + l31) >> 1) * 64;
#pragma unroll
  for (int nj = 0; nj < 2; ++nj) prB[nj] = ((wn + nj * 32 + l31) >> 1) * 64;

  f32x16 acc[4][2];
#pragma unroll
  for (int mi = 0; mi < 4; ++mi)
#pragma unroll
    for (int nj = 0; nj < 2; ++nj)
#pragma unroll
      for (int e = 0; e < 16; ++e) acc[mi][nj][e] = 0.f;

#define STG_A(kt_) do { const int b_ = (kt_) & 3; const int ko_ = (kt_) * 32; \
    async16(aS0 + ko_, &As[b_][d0]); async16(aS1 + ko_, &As[b_][d1]); } while (0)
#define STG_B(kt_) do { const int b_ = (kt_) & 3; const int ko_ = (kt_) * 32; \
    async16(bS0 + ko_, &Bs[b_][d0]); async16(bS1 + ko_, &Bs[b_][d1]); } while (0)

  const int NT = K >> 5;
  // prologue: tiles 0,1,2 in flight (12 loads/thread); retire tile 0's 4.
  STG_A(0); STG_B(0); STG_A(1); STG_B(1); STG_A(2); STG_B(2);
  asm volatile("s_waitcnt vmcnt(8)" ::: "memory");
  asm volatile("s_barrier" ::: "memory");

  for (int kt = 0; kt < NT; ++kt) {
    const int bi = kt & 3;
    const unsigned short* as_ = As[bi];
    const unsigned short* bs_ = Bs[bi];

    // stage tile kt+3 FIRST (max time in flight); writes buffer (kt-1)&3,
    // whose reads completed before the previous barrier -> safe.
    if (kt + 3 < NT) { STG_A(kt + 3); STG_B(kt + 3); }

    // fragment reads: B first (first MFMA needs af[0][0]+bfv[0][0])
    bf16x8 bfv[2][2], af[4][2];
#pragma unroll
    for (int nj = 0; nj < 2; ++nj) {
      bfv[nj][0] = *(const bf16x8*)(bs_ + prB[nj] + pg0);
      bfv[nj][1] = *(const bf16x8*)(bs_ + prB[nj] + pg1);
    }
#pragma unroll
    for (int mi = 0; mi < 4; ++mi) {
      af[mi][0] = *(const bf16x8*)(as_ + prA[mi] + pg0);
      af[mi][1] = *(const bf16x8*)(as_ + prA[mi] + pg1);
    }

    // 16 MFMA; compiler interleaves with the ds_reads via counted lgkmcnt
#pragma unroll
    for (int mi = 0; mi < 4; ++mi)
#pragma unroll
      for (int nj = 0; nj < 2; ++nj) {
        acc[mi][nj] = __builtin_amdgcn_mfma_f32_32x32x16_bf16(af[mi][0], bfv[nj][0], acc[mi][nj], 0, 0, 0);
        acc[mi][nj] = __builtin_amdgcn_mfma_f32_32x32x16_bf16(af[mi][1], bfv[nj][1], acc[mi][nj], 0, 0, 0);
      }

    // counted wait: retire tile kt+1's loads (issued 2 iters ago); keep the
    // 8 newest (tiles kt+2, kt+3) in flight. Tail cascade as staging stops.
    if (kt + 3 < NT) {
      asm volatile("s_waitcnt vmcnt(8)" ::: "memory");
    } else if (kt + 2 < NT) {
      asm volatile("s_waitcnt vmcnt(4)" ::: "memory");
    } else if (kt + 1 < NT) {
      asm volatile("s_waitcnt vmcnt(0)" ::: "memory");
    }
    asm volatile("s_barrier" ::: "memory");
  }
#undef STG_A
#undef STG_B

  // epilogue: col = l31, row = (reg&3) + 8*(reg>>2) + 4*lhi
#pragma unroll
  for (int mi = 0; mi < 4; ++mi) {
#pragma unroll
    for (int nj = 0; nj < 2; ++nj) {
      int gc = bn0 + wn + nj * 32 + l31;
      float bsv = bias[gc];
#pragma unroll
      for (int reg = 0; reg < 16; ++reg) {
        int gr = bm0 + wm + mi * 32 + (reg & 3) + 8 * (reg >> 2) + 4 * lhi;
        C[(size_t)gr * N + gc] = f2b(acc[mi][nj][reg] + bsv);
      }
    }
  }
}

// --------------------------- C = A * Bt^T + bias ----------------------------
// (128x128 tile, kept for the final projection where N=1024 would underfill
// the grid at 256^2.)
template <typename OutT>
__global__ __launch_bounds__(256) void gemm_bt(const unsigned short* __restrict__ A,
                                               const unsigned short* __restrict__ Bt,
                                               const float* __restrict__ bias,
                                               OutT* __restrict__ C, int M, int N, int K) {
  __shared__ __align__(16) unsigned short As[128 * 64];
  __shared__ __align__(16) unsigned short Bs[128 * 64];
  const int t = threadIdx.x;
  const int lane = t & 63, w = t >> 6;
  const int wm = (w >> 1) * 64, wn = (w & 1) * 64;
  const int l31 = lane & 31, lhi = lane >> 5;
  const int bm0 = blockIdx.y * 128, bn0 = blockIdx.x * 128;

  f32x16 acc[2][2];
#pragma unroll
  for (int i = 0; i < 2; ++i)
#pragma unroll
    for (int j = 0; j < 2; ++j)
#pragma unroll
      for (int e = 0; e < 16; ++e) acc[i][j][e] = 0.f;

  const int swz = l31 & 7;
  const int qoff = 2 * ((l31 >> 4) & 1);

  for (int k0 = 0; k0 < K; k0 += 64) {
    __syncthreads();
#pragma unroll
    for (int j = 0; j < 4; ++j) {
      int slot = j * 256 + t;
      int r = slot >> 3;
      int p = slot & 7;
      int c = (((p ^ (r & 7)) - 2 * ((r >> 4) & 1)) & 7) * 8;
      async16(A + (size_t)(bm0 + r) * K + k0 + c, As + slot * 8);
      async16(Bt + (size_t)(bn0 + r) * K + k0 + c, Bs + slot * 8);
    }
    __syncthreads();
#pragma unroll
    for (int kk = 0; kk < 64; kk += 16) {
      const int kg = kk >> 3;
      const int pg = ((((kg + lhi + qoff) & 7) ^ swz) << 3);
      bf16x8 af[2], bfr[2];
#pragma unroll
      for (int i = 0; i < 2; ++i)
        af[i] = *(const bf16x8*)(As + (wm + i * 32 + l31) * 64 + pg);
#pragma unroll
      for (int j = 0; j < 2; ++j)
        bfr[j] = *(const bf16x8*)(Bs + (wn + j * 32 + l31) * 64 + pg);
#pragma unroll
      for (int i = 0; i < 2; ++i)
#pragma unroll
        for (int j = 0; j < 2; ++j)
          acc[i][j] = __builtin_amdgcn_mfma_f32_32x32x16_bf16(af[i], bfr[j], acc[i][j], 0, 0, 0);
    }
  }

#pragma unroll
  for (int i = 0; i < 2; ++i) {
#pragma unroll
    for (int j = 0; j < 2; ++j) {
      int gc = bn0 + wn + j * 32 + l31;
      float bsv = bias[gc];
#pragma unroll
      for (int reg = 0; reg < 16; ++reg) {
        int gr = bm0 + wm + i * 32 + (reg & 3) + 8 * (reg >> 2) + 4 * lhi;
        float vv = acc[i][j][reg] + bsv;
        if constexpr (sizeof(OutT) == 2)
          C[(size_t)gr * N + gc] = (OutT)f2b(vv);
        else
          C[(size_t)gr * N + gc] = vv;
      }
    }
  }
}

// ------------------- per-position head-softmax attention --------------------
__global__ __launch_bounds__(256) void attn_scatter(const unsigned short* __restrict__ qkv,
                                                    unsigned short* __restrict__ t) {
  __shared__ __align__(16) unsigned short vs[4][1024];
  __shared__ float ps[4][16 * 17];
  const int w = threadIdx.x >> 6, lane = threadIdx.x & 63;
  const int pos = blockIdx.x * 4 + w;  // 0..8191
  const int b = pos >> 11, s = pos & 2047;
  const unsigned short* row = qkv + (size_t)pos * 6144;
  unsigned short* vw = vs[w];
  float* pw = ps[w];
  const int lr = lane & 15, lq = lane >> 4;

  {
    const uint4* sv = (const uint4*)(row + 5120);
    uint4* dv = (uint4*)vw;
    dv[lane * 2] = sv[lane * 2];
    dv[lane * 2 + 1] = sv[lane * 2 + 1];
  }
  bf16x8 kf0 = *(const bf16x8*)(row + 4096 + lr * 64 + lq * 8);
  bf16x8 kf1 = *(const bf16x8*)(row + 4096 + lr * 64 + 32 + lq * 8);

  bf16x8 vf[4];
#pragma unroll
  for (int dc = 0; dc < 4; ++dc) {
#pragma unroll
    for (int j = 0; j < 8; ++j) vf[dc][j] = (__bf16)0.0f;
    if (lq < 2) {
      const __bf16* vb = (const __bf16*)vw;
#pragma unroll
      for (int j = 0; j < 8; ++j)
        vf[dc][j] = vb[(lq * 8 + j) * 64 + dc * 16 + lr];
    }
  }

  f32x4 acc[4];
#pragma unroll
  for (int dc = 0; dc < 4; ++dc) acc[dc] = (f32x4){0.f, 0.f, 0.f, 0.f};

#pragma unroll
  for (int qi = 0; qi < 4; ++qi) {
    bf16x8 qf0 = *(const bf16x8*)(row + qi * 1024 + lr * 64 + lq * 8);
    bf16x8 qf1 = *(const bf16x8*)(row + qi * 1024 + lr * 64 + 32 + lq * 8);
    f32x4 sc = {0.f, 0.f, 0.f, 0.f};
    sc = __builtin_amdgcn_mfma_f32_16x16x32_bf16(qf0, kf0, sc, 0, 0, 0);
    sc = __builtin_amdgcn_mfma_f32_16x16x32_bf16(qf1, kf1, sc, 0, 0, 0);
#pragma unroll
    for (int r = 0; r < 4; ++r) {
      float e = __expf(sc[r] * 0.125f);
      float sum = e;
#pragma unroll
      for (int d = 1; d < 16; d <<= 1) sum += __shfl_xor(sum, d);
      pw[(lq * 4 + r) * 17 + lr] = e / sum;
    }
    bf16x8 pf;
#pragma unroll
    for (int j = 0; j < 8; ++j) pf[j] = (__bf16)0.0f;
    if (lq < 2) {
#pragma unroll
      for (int j = 0; j < 8; ++j) pf[j] = (__bf16)pw[lr * 17 + lq * 8 + j];
    }
#pragma unroll
    for (int dc = 0; dc < 4; ++dc)
      acc[dc] = __builtin_amdgcn_mfma_f32_16x16x32_bf16(vf[dc], pf, acc[dc], 0, 0, 0);
  }

  size_t base = ((size_t)(b * 2048 + 128 * lr + (s >> 4))) * 1024 + 64 * (s & 15) + lq * 4;
#pragma unroll
  for (int dc = 0; dc < 4; ++dc) {
    uint2 u;
    u.x = (unsigned)f2b(acc[dc][0]) | ((unsigned)f2b(acc[dc][1]) << 16);
    u.y = (unsigned)f2b(acc[dc][2]) | ((unsigned)f2b(acc[dc][3]) << 16);
    *(uint2*)(t + base + dc * 16) = u;
  }
}

// ---------------------------------------------------------------------------
extern "C" void kernel_launch(void* const* d_in, const int* in_sizes, int n_in,
                              void* d_out, int out_size, void* d_ws, size_t ws_size,
                              hipStream_t stream) {
  const float* x  = (const float*)d_in[0];
  const float* Wq = (const float*)d_in[1];
  const float* bq = (const float*)d_in[2];
  const float* Wk = (const float*)d_in[3];
  const float* bk = (const float*)d_in[4];
  const float* Wv = (const float*)d_in[5];
  const float* bv = (const float*)d_in[6];
  const float* Wo = (const float*)d_in[7];
  const float* bo = (const float*)d_in[8];
  float* out = (float*)d_out;

  char* ws = (char*)d_ws;
  unsigned short* xb      = (unsigned short*)(ws + 0);         // 8192x1024 bf16 (16MB); aliased as t later
  unsigned short* wcat    = (unsigned short*)(ws + 16777216);  // 6144x1024 bf16 (12MB): Wq|Wk|Wv
  unsigned short* wo_b    = (unsigned short*)(ws + 29360128);  // 1024x1024 bf16 (2MB)
  float*          biascat = (float*)(ws + 31457280);           // 6144 fp32
  unsigned short* qkv     = (unsigned short*)(ws + 31481856);  // 8192x6144 bf16 (96MB)
  unsigned short* t       = xb;  // safe alias: xb dead after QKV GEMM

  cvt_all<<<15384, 256, 0, stream>>>(x, Wq, Wk, Wv, Wo, bq, bk, bv, xb, wcat, wo_b, biascat);

  // QKV: (8192x1024) x (6144x1024)^T -> 8192x6144 bf16  (256^2 deep pipeline)
  gemm256<<<dim3(24, 32), 512, 0, stream>>>(xb, wcat, biascat, qkv, 8192, 6144, 1024);
  // attention + permute/sum scatter -> t (8192x1024 bf16)
  attn_scatter<<<2048, 256, 0, stream>>>(qkv, t);
  // final: t x Wo^T + bo -> fp32 out
  gemm_bt<float><<<dim3(8, 64), 256, 0, stream>>>(t, wo_b, bo, out, 8192, 1024, 1024);
}

// Round 5
// 273.260 us; speedup vs baseline: 1.1125x; 1.1125x over previous
//
#include <hip/hip_runtime.h>

// ---------------------------------------------------------------------------
// MultiQueryAttention: B=4 S=2048 E=1024 H=16 D=64 Q=4
// ref: q=x@Wq^T+bq (per qi), k=x@Wk^T+bk, v=x@Wv^T+bv
//      scores[qi,b,s,h,g] = dot_d(q[h],k[g])/8 ; softmax over g (16 heads!)
//      out[qi,b,s,h,d] = sum_g p*v[g,d]
//      t[b, 128h + s/16, 64(s%16)+d] = sum_qi out   (torch transpose+reshape)
//      final = t @ Wo^T + bo   (fp32 out)
// ---------------------------------------------------------------------------

typedef __bf16 bf16x8 __attribute__((ext_vector_type(8)));
typedef float f32x4 __attribute__((ext_vector_type(4)));
typedef float f32x16 __attribute__((ext_vector_type(16)));

__device__ __forceinline__ unsigned short f2b(float f) {
  unsigned u = __float_as_uint(f);
  return (unsigned short)((u + 0x7fffu + ((u >> 16) & 1u)) >> 16);  // RNE
}

__device__ __forceinline__ void async16(const void* g, void* l) {
  __builtin_amdgcn_global_load_lds(
      (const __attribute__((address_space(1))) void*)g,
      (__attribute__((address_space(3))) void*)l, 16, 0, 0);
}

// ------------------- fused fp32->bf16 convert + bias concat ------------------
__global__ __launch_bounds__(256) void cvt_all(
    const float* __restrict__ x, const float* __restrict__ Wq, const float* __restrict__ Wk,
    const float* __restrict__ Wv, const float* __restrict__ Wo, const float* __restrict__ bq,
    const float* __restrict__ bk, const float* __restrict__ bv,
    unsigned short* __restrict__ xb, unsigned short* __restrict__ wcat,
    unsigned short* __restrict__ wo_b, float* __restrict__ biascat) {
  if (blockIdx.x >= 15360) {
    int j = (blockIdx.x - 15360) * 256 + threadIdx.x;  // 0..6143
    if (j < 6144) {
      float v = (j < 4096) ? bq[j] : (j < 5120 ? bk[j - 4096] : bv[j - 5120]);
      biascat[j] = v;
    }
    return;
  }
  int i = blockIdx.x * 256 + threadIdx.x;
  const float* s;
  unsigned short* d;
  int off;
  if (i < 2097152)      { s = x;  d = xb;             off = i; }
  else if (i < 3145728) { s = Wq; d = wcat;           off = i - 2097152; }
  else if (i < 3407872) { s = Wk; d = wcat + 4194304; off = i - 3145728; }
  else if (i < 3670016) { s = Wv; d = wcat + 5242880; off = i - 3407872; }
  else                  { s = Wo; d = wo_b;           off = i - 3670016; }
  float4 v = ((const float4*)s)[off];
  uint2 o;
  o.x = (unsigned)f2b(v.x) | ((unsigned)f2b(v.y) << 16);
  o.y = (unsigned)f2b(v.z) | ((unsigned)f2b(v.w) << 16);
  ((uint2*)d)[off] = o;
}

// ------------------ 256x256 deep-pipelined GEMM (QKV) -----------------------
// C = A * Bt^T + bias, bf16 out. M%256==0, N%256==0, K%32==0, K>=64.
// 8 waves as 2(M)x4(N); per-wave C = 128x64 = 4x2 of 32x32 MFMA frags.
// LDS: 4-deep ring of BK=32 K-tiles (A:16KB + B:16KB each) = 128 KiB.
//
// PAIR-ROW SWIZZLE (R2, verified conflict-free: SQ_LDS_BANK_CONFLICT==0):
// granule g (16B) of row r lives at phys slot p = (2g+(r&1)) ^ ((r>>1)&7)
// within pair (r>>1). Store: linear LDS dest (global_load_lds), pre-swizzled
// GLOBAL source. Read: p = (4ks + 2*lhi + (l31&1)) ^ ((l31>>1)&7).
//
// R3 (verified best: 114.3us, MfmaUtil 39%): ONE barrier per K-tile, counted
// vmcnt(4), prefetch distance 1, staging issued mid-iteration. R4's deeper
// prefetch (dist-2/vmcnt(8)/stage-at-top) REGRESSED to 151us -> reverted;
// load latency is not the residual stall.
// R5: + s_setprio(1/0) around the MFMA cluster (T5). Mechanism: 2 blocks/CU
// free-run; per-CU per-iter LDS pipe (~1150cy) and MFMA pipe (~1030cy) are
// measured nearly SERIALIZED (2850cy/iter). Prioritizing MFMA-phase waves
// over the co-block's ds_read-phase waves pushes the two blocks into
// anti-phase so the two pipes overlap.
__global__ __launch_bounds__(512, 2) void gemm256(
    const unsigned short* __restrict__ A, const unsigned short* __restrict__ Bt,
    const float* __restrict__ bias, unsigned short* __restrict__ C,
    int M, int N, int K) {
  __shared__ __align__(16) unsigned short As[4][8192];
  __shared__ __align__(16) unsigned short Bs[4][8192];
  const int t = threadIdx.x;
  const int lane = t & 63, w = t >> 6;
  const int l31 = lane & 31, lhi = lane >> 5;
  const int wm = (w >> 2) * 128, wn = (w & 3) * 64;
  const int bm0 = blockIdx.y * 256, bn0 = blockIdx.x * 256;

  // ---- staging: thread t handles slot t (rows 0..127) and t+512 (rows
  // 128..255); source pre-swizzled, LDS dest linear.
  const int p0 = t & 7, pr0 = t >> 3;
  const int u0 = p0 ^ (pr0 & 7);
  const size_t aoff0 = (size_t)(2 * pr0 + (u0 & 1)) * K + (u0 >> 1) * 8;
  const unsigned short* aS0 = A + (size_t)bm0 * K + aoff0;
  const unsigned short* aS1 = aS0 + (size_t)128 * K;  // slot t+512: same u (64%8==0)
  const unsigned short* bS0 = Bt + (size_t)bn0 * K + aoff0;
  const unsigned short* bS1 = bS0 + (size_t)128 * K;
  const int d0 = t * 8, d1 = d0 + 4096;  // linear LDS dests (elements)

  // ---- read offsets
  const int plo = 2 * lhi + (l31 & 1);
  const int pswz = (l31 >> 1) & 7;
  const int pg0 = ((0 + plo) ^ pswz) * 8;  // ks=0
  const int pg1 = ((4 + plo) ^ pswz) * 8;  // ks=1
  int prA[4], prB[2];
#pragma unroll
  for (int mi = 0; mi < 4; ++mi) prA[mi] = ((wm + mi * 32 + l31) >> 1) * 64;
#pragma unroll
  for (int nj = 0; nj < 2; ++nj) prB[nj] = ((wn + nj * 32 + l31) >> 1) * 64;

  f32x16 acc[4][2];
#pragma unroll
  for (int mi = 0; mi < 4; ++mi)
#pragma unroll
    for (int nj = 0; nj < 2; ++nj)
#pragma unroll
      for (int e = 0; e < 16; ++e) acc[mi][nj][e] = 0.f;

#define STG_A(kt_) do { const int b_ = (kt_) & 3; const int ko_ = (kt_) * 32; \
    async16(aS0 + ko_, &As[b_][d0]); async16(aS1 + ko_, &As[b_][d1]); } while (0)
#define STG_B(kt_) do { const int b_ = (kt_) & 3; const int ko_ = (kt_) * 32; \
    async16(bS0 + ko_, &Bs[b_][d0]); async16(bS1 + ko_, &Bs[b_][d1]); } while (0)

  const int NT = K >> 5;
  // prologue: tiles 0 and 1 in flight; retire tile 0 (tile 1's 4 stay out)
  STG_A(0); STG_B(0); STG_A(1); STG_B(1);
  asm volatile("s_waitcnt vmcnt(4)" ::: "memory");
  asm volatile("s_barrier" ::: "memory");

  for (int kt = 0; kt < NT; ++kt) {
    const int bi = kt & 3;
    const unsigned short* as_ = As[bi];
    const unsigned short* bs_ = Bs[bi];

    // all 12 fragment reads for this K-tile (both ksteps)
    bf16x8 af[4][2], bfv[2][2];
#pragma unroll
    for (int mi = 0; mi < 4; ++mi) {
      af[mi][0] = *(const bf16x8*)(as_ + prA[mi] + pg0);
      af[mi][1] = *(const bf16x8*)(as_ + prA[mi] + pg1);
    }
#pragma unroll
    for (int nj = 0; nj < 2; ++nj) {
      bfv[nj][0] = *(const bf16x8*)(bs_ + prB[nj] + pg0);
      bfv[nj][1] = *(const bf16x8*)(bs_ + prB[nj] + pg1);
    }
    // stage tile kt+2 (writes buffer kt-2: last read 2 barriers ago -> safe)
    if (kt + 2 < NT) { STG_A(kt + 2); STG_B(kt + 2); }

    // 16 MFMA; compiler interleaves with the ds_reads via counted lgkmcnt.
    // T5: boost priority during the MFMA burst so this wave outranks
    // co-resident waves issuing LDS reads -> cross-block pipe overlap.
    __builtin_amdgcn_s_setprio(1);
#pragma unroll
    for (int mi = 0; mi < 4; ++mi)
#pragma unroll
      for (int nj = 0; nj < 2; ++nj) {
        acc[mi][nj] = __builtin_amdgcn_mfma_f32_32x32x16_bf16(af[mi][0], bfv[nj][0], acc[mi][nj], 0, 0, 0);
        acc[mi][nj] = __builtin_amdgcn_mfma_f32_32x32x16_bf16(af[mi][1], bfv[nj][1], acc[mi][nj], 0, 0, 0);
      }
    __builtin_amdgcn_s_setprio(0);

    // counted wait: retire tile kt+1's 4 loads (oldest); keep tile kt+2's 4
    // in flight. Tail: drain only when nothing newer was issued.
    if (kt + 2 < NT) {
      asm volatile("s_waitcnt vmcnt(4)" ::: "memory");
    } else if (kt + 1 < NT) {
      asm volatile("s_waitcnt vmcnt(0)" ::: "memory");
    }
    asm volatile("s_barrier" ::: "memory");
  }
#undef STG_A
#undef STG_B

  // epilogue: col = l31, row = (reg&3) + 8*(reg>>2) + 4*lhi
#pragma unroll
  for (int mi = 0; mi < 4; ++mi) {
#pragma unroll
    for (int nj = 0; nj < 2; ++nj) {
      int gc = bn0 + wn + nj * 32 + l31;
      float bsv = bias[gc];
#pragma unroll
      for (int reg = 0; reg < 16; ++reg) {
        int gr = bm0 + wm + mi * 32 + (reg & 3) + 8 * (reg >> 2) + 4 * lhi;
        C[(size_t)gr * N + gc] = f2b(acc[mi][nj][reg] + bsv);
      }
    }
  }
}

// --------------------------- C = A * Bt^T + bias ----------------------------
// (128x128 tile, kept for the final projection where N=1024 would underfill
// the grid at 256^2.)
template <typename OutT>
__global__ __launch_bounds__(256) void gemm_bt(const unsigned short* __restrict__ A,
                                               const unsigned short* __restrict__ Bt,
                                               const float* __restrict__ bias,
                                               OutT* __restrict__ C, int M, int N, int K) {
  __shared__ __align__(16) unsigned short As[128 * 64];
  __shared__ __align__(16) unsigned short Bs[128 * 64];
  const int t = threadIdx.x;
  const int lane = t & 63, w = t >> 6;
  const int wm = (w >> 1) * 64, wn = (w & 1) * 64;
  const int l31 = lane & 31, lhi = lane >> 5;
  const int bm0 = blockIdx.y * 128, bn0 = blockIdx.x * 128;

  f32x16 acc[2][2];
#pragma unroll
  for (int i = 0; i < 2; ++i)
#pragma unroll
    for (int j = 0; j < 2; ++j)
#pragma unroll
      for (int e = 0; e < 16; ++e) acc[i][j][e] = 0.f;

  const int swz = l31 & 7;
  const int qoff = 2 * ((l31 >> 4) & 1);

  for (int k0 = 0; k0 < K; k0 += 64) {
    __syncthreads();
#pragma unroll
    for (int j = 0; j < 4; ++j) {
      int slot = j * 256 + t;
      int r = slot >> 3;
      int p = slot & 7;
      int c = (((p ^ (r & 7)) - 2 * ((r >> 4) & 1)) & 7) * 8;
      async16(A + (size_t)(bm0 + r) * K + k0 + c, As + slot * 8);
      async16(Bt + (size_t)(bn0 + r) * K + k0 + c, Bs + slot * 8);
    }
    __syncthreads();
#pragma unroll
    for (int kk = 0; kk < 64; kk += 16) {
      const int kg = kk >> 3;
      const int pg = ((((kg + lhi + qoff) & 7) ^ swz) << 3);
      bf16x8 af[2], bfr[2];
#pragma unroll
      for (int i = 0; i < 2; ++i)
        af[i] = *(const bf16x8*)(As + (wm + i * 32 + l31) * 64 + pg);
#pragma unroll
      for (int j = 0; j < 2; ++j)
        bfr[j] = *(const bf16x8*)(Bs + (wn + j * 32 + l31) * 64 + pg);
#pragma unroll
      for (int i = 0; i < 2; ++i)
#pragma unroll
        for (int j = 0; j < 2; ++j)
          acc[i][j] = __builtin_amdgcn_mfma_f32_32x32x16_bf16(af[i], bfr[j], acc[i][j], 0, 0, 0);
    }
  }

#pragma unroll
  for (int i = 0; i < 2; ++i) {
#pragma unroll
    for (int j = 0; j < 2; ++j) {
      int gc = bn0 + wn + j * 32 + l31;
      float bsv = bias[gc];
#pragma unroll
      for (int reg = 0; reg < 16; ++reg) {
        int gr = bm0 + wm + i * 32 + (reg & 3) + 8 * (reg >> 2) + 4 * lhi;
        float vv = acc[i][j][reg] + bsv;
        if constexpr (sizeof(OutT) == 2)
          C[(size_t)gr * N + gc] = (OutT)f2b(vv);
        else
          C[(size_t)gr * N + gc] = vv;
      }
    }
  }
}

// ------------------- per-position head-softmax attention --------------------
__global__ __launch_bounds__(256) void attn_scatter(const unsigned short* __restrict__ qkv,
                                                    unsigned short* __restrict__ t) {
  __shared__ __align__(16) unsigned short vs[4][1024];
  __shared__ float ps[4][16 * 17];
  const int w = threadIdx.x >> 6, lane = threadIdx.x & 63;
  const int pos = blockIdx.x * 4 + w;  // 0..8191
  const int b = pos >> 11, s = pos & 2047;
  const unsigned short* row = qkv + (size_t)pos * 6144;
  unsigned short* vw = vs[w];
  float* pw = ps[w];
  const int lr = lane & 15, lq = lane >> 4;

  {
    const uint4* sv = (const uint4*)(row + 5120);
    uint4* dv = (uint4*)vw;
    dv[lane * 2] = sv[lane * 2];
    dv[lane * 2 + 1] = sv[lane * 2 + 1];
  }
  bf16x8 kf0 = *(const bf16x8*)(row + 4096 + lr * 64 + lq * 8);
  bf16x8 kf1 = *(const bf16x8*)(row + 4096 + lr * 64 + 32 + lq * 8);

  bf16x8 vf[4];
#pragma unroll
  for (int dc = 0; dc < 4; ++dc) {
#pragma unroll
    for (int j = 0; j < 8; ++j) vf[dc][j] = (__bf16)0.0f;
    if (lq < 2) {
      const __bf16* vb = (const __bf16*)vw;
#pragma unroll
      for (int j = 0; j < 8; ++j)
        vf[dc][j] = vb[(lq * 8 + j) * 64 + dc * 16 + lr];
    }
  }

  f32x4 acc[4];
#pragma unroll
  for (int dc = 0; dc < 4; ++dc) acc[dc] = (f32x4){0.f, 0.f, 0.f, 0.f};

#pragma unroll
  for (int qi = 0; qi < 4; ++qi) {
    bf16x8 qf0 = *(const bf16x8*)(row + qi * 1024 + lr * 64 + lq * 8);
    bf16x8 qf1 = *(const bf16x8*)(row + qi * 1024 + lr * 64 + 32 + lq * 8);
    f32x4 sc = {0.f, 0.f, 0.f, 0.f};
    sc = __builtin_amdgcn_mfma_f32_16x16x32_bf16(qf0, kf0, sc, 0, 0, 0);
    sc = __builtin_amdgcn_mfma_f32_16x16x32_bf16(qf1, kf1, sc, 0, 0, 0);
#pragma unroll
    for (int r = 0; r < 4; ++r) {
      float e = __expf(sc[r] * 0.125f);
      float sum = e;
#pragma unroll
      for (int d = 1; d < 16; d <<= 1) sum += __shfl_xor(sum, d);
      pw[(lq * 4 + r) * 17 + lr] = e / sum;
    }
    bf16x8 pf;
#pragma unroll
    for (int j = 0; j < 8; ++j) pf[j] = (__bf16)0.0f;
    if (lq < 2) {
#pragma unroll
      for (int j = 0; j < 8; ++j) pf[j] = (__bf16)pw[lr * 17 + lq * 8 + j];
    }
#pragma unroll
    for (int dc = 0; dc < 4; ++dc)
      acc[dc] = __builtin_amdgcn_mfma_f32_16x16x32_bf16(vf[dc], pf, acc[dc], 0, 0, 0);
  }

  size_t base = ((size_t)(b * 2048 + 128 * lr + (s >> 4))) * 1024 + 64 * (s & 15) + lq * 4;
#pragma unroll
  for (int dc = 0; dc < 4; ++dc) {
    uint2 u;
    u.x = (unsigned)f2b(acc[dc][0]) | ((unsigned)f2b(acc[dc][1]) << 16);
    u.y = (unsigned)f2b(acc[dc][2]) | ((unsigned)f2b(acc[dc][3]) << 16);
    *(uint2*)(t + base + dc * 16) = u;
  }
}

// ---------------------------------------------------------------------------
extern "C" void kernel_launch(void* const* d_in, const int* in_sizes, int n_in,
                              void* d_out, int out_size, void* d_ws, size_t ws_size,
                              hipStream_t stream) {
  const float* x  = (const float*)d_in[0];
  const float* Wq = (const float*)d_in[1];
  const float* bq = (const float*)d_in[2];
  const float* Wk = (const float*)d_in[3];
  const float* bk = (const float*)d_in[4];
  const float* Wv = (const float*)d_in[5];
  const float* bv = (const float*)d_in[6];
  const float* Wo = (const float*)d_in[7];
  const float* bo = (const float*)d_in[8];
  float* out = (float*)d_out;

  char* ws = (char*)d_ws;
  unsigned short* xb      = (unsigned short*)(ws + 0);         // 8192x1024 bf16 (16MB); aliased as t later
  unsigned short* wcat    = (unsigned short*)(ws + 16777216);  // 6144x1024 bf16 (12MB): Wq|Wk|Wv
  unsigned short* wo_b    = (unsigned short*)(ws + 29360128);  // 1024x1024 bf16 (2MB)
  float*          biascat = (float*)(ws + 31457280);           // 6144 fp32
  unsigned short* qkv     = (unsigned short*)(ws + 31481856);  // 8192x6144 bf16 (96MB)
  unsigned short* t       = xb;  // safe alias: xb dead after QKV GEMM

  cvt_all<<<15384, 256, 0, stream>>>(x, Wq, Wk, Wv, Wo, bq, bk, bv, xb, wcat, wo_b, biascat);

  // QKV: (8192x1024) x (6144x1024)^T -> 8192x6144 bf16  (256^2 deep pipeline)
  gemm256<<<dim3(24, 32), 512, 0, stream>>>(xb, wcat, biascat, qkv, 8192, 6144, 1024);
  // attention + permute/sum scatter -> t (8192x1024 bf16)
  attn_scatter<<<2048, 256, 0, stream>>>(qkv, t);
  // final: t x Wo^T + bo -> fp32 out
  gemm_bt<float><<<dim3(8, 64), 256, 0, stream>>>(t, wo_b, bo, out, 8192, 1024, 1024);
}